// Round 1
// baseline (312.143 us; speedup 1.0000x reference)
//
#include <hip/hip_runtime.h>
#include <hip/hip_bf16.h>

// LSS (Lift-Splat-Shoot) voxel pooling.
// B=2, N=6, D=112, H=16, W=44, C=80, BEV 128x128.
// depth = softmax(depth_logits, axis=D); feat = depth (x) context;
// bev[b, geom_idx] += feat  -> output [B, C, 128, 128].

constexpr int B = 2, N = 6, D = 112, H = 16, W = 44, C = 80;
constexpr int HW = H * W;                 // 704
constexpr int NPIX = B * N * HW;          // 8448 pixels
constexpr int NV = 128 * 128;             // 16384 voxels

// One block per pixel: softmax over D in LDS, ctx[C] staged in LDS,
// then D*C=8960 atomic adds into voxel-major ws[b][v][c].
__global__ __launch_bounds__(256) void lift_splat_kernel(
    const float* __restrict__ logits, const float* __restrict__ ctx,
    const int* __restrict__ gidx, float* __restrict__ ws) {
  const int t = threadIdx.x;
  const int pix = blockIdx.x;
  const int hw = pix % HW;
  const int bn = pix / HW;       // b*N + n
  const int b = bn / N;

  const float* lg = logits + (size_t)bn * (D * HW) + hw;  // stride HW per d
  const int* gi = gidx + (size_t)bn * (D * HW) + hw;
  const float* cx = ctx + (size_t)bn * (C * HW) + hw;     // stride HW per c

  __shared__ float s_prob[D];
  __shared__ float s_ctx[C];
  __shared__ int s_idx[D];
  __shared__ float red[256];

  float v = -3.0e38f;
  if (t < D) {
    v = lg[(size_t)t * HW];
    s_idx[t] = gi[(size_t)t * HW];
  }
  if (t < C) s_ctx[t] = cx[(size_t)t * HW];

  // block max
  red[t] = v;
  __syncthreads();
#pragma unroll
  for (int s = 128; s >= 1; s >>= 1) {
    if (t < s) red[t] = fmaxf(red[t], red[t + s]);
    __syncthreads();
  }
  const float m = red[0];
  __syncthreads();

  // exp + block sum
  float e = 0.0f;
  if (t < D) e = __expf(v - m);
  red[t] = e;
  __syncthreads();
#pragma unroll
  for (int s = 128; s >= 1; s >>= 1) {
    if (t < s) red[t] += red[t + s];
    __syncthreads();
  }
  const float inv = 1.0f / red[0];
  if (t < D) s_prob[t] = e * inv;
  __syncthreads();

  // scatter: ws[b][idx[d]][c] += prob[d] * ctx[c]
  float* wsb = ws + (size_t)b * ((size_t)NV * C);
  for (int f = t; f < D * C; f += 256) {
    const int d = f / C;
    const int c = f - d * C;
    atomicAdd(&wsb[(size_t)s_idx[d] * C + c], s_prob[d] * s_ctx[c]);
  }
}

// Fallback: atomics straight into channel-major output (out must be zeroed).
__global__ __launch_bounds__(256) void lift_splat_direct_kernel(
    const float* __restrict__ logits, const float* __restrict__ ctx,
    const int* __restrict__ gidx, float* __restrict__ out) {
  const int t = threadIdx.x;
  const int pix = blockIdx.x;
  const int hw = pix % HW;
  const int bn = pix / HW;
  const int b = bn / N;

  const float* lg = logits + (size_t)bn * (D * HW) + hw;
  const int* gi = gidx + (size_t)bn * (D * HW) + hw;
  const float* cx = ctx + (size_t)bn * (C * HW) + hw;

  __shared__ float s_prob[D];
  __shared__ float s_ctx[C];
  __shared__ int s_idx[D];
  __shared__ float red[256];

  float v = -3.0e38f;
  if (t < D) {
    v = lg[(size_t)t * HW];
    s_idx[t] = gi[(size_t)t * HW];
  }
  if (t < C) s_ctx[t] = cx[(size_t)t * HW];

  red[t] = v;
  __syncthreads();
#pragma unroll
  for (int s = 128; s >= 1; s >>= 1) {
    if (t < s) red[t] = fmaxf(red[t], red[t + s]);
    __syncthreads();
  }
  const float m = red[0];
  __syncthreads();

  float e = 0.0f;
  if (t < D) e = __expf(v - m);
  red[t] = e;
  __syncthreads();
#pragma unroll
  for (int s = 128; s >= 1; s >>= 1) {
    if (t < s) red[t] += red[t + s];
    __syncthreads();
  }
  const float inv = 1.0f / red[0];
  if (t < D) s_prob[t] = e * inv;
  __syncthreads();

  for (int f = t; f < D * C; f += 256) {
    const int d = f / C;
    const int c = f - d * C;
    atomicAdd(&out[((size_t)(b * C + c)) * NV + s_idx[d]],
              s_prob[d] * s_ctx[c]);
  }
}

// ws[b][v][c] (voxel-major) -> out[b][c][v] (channel-major), coalesced stores.
__global__ __launch_bounds__(256) void transpose_kernel(
    const float* __restrict__ ws, float* __restrict__ out) {
  const int i = blockIdx.x * blockDim.x + threadIdx.x;
  if (i >= B * C * NV) return;
  const int v = i % NV;
  const int bc = i / NV;
  const int c = bc % C;
  const int b = bc / C;
  out[i] = ws[((size_t)b * NV + v) * (size_t)C + c];
}

extern "C" void kernel_launch(void* const* d_in, const int* in_sizes, int n_in,
                              void* d_out, int out_size, void* d_ws,
                              size_t ws_size, hipStream_t stream) {
  const float* logits = (const float*)d_in[0];
  const float* ctx = (const float*)d_in[1];
  const int* gidx = (const int*)d_in[2];
  float* out = (float*)d_out;

  const size_t ws_needed = (size_t)B * NV * C * sizeof(float);
  if (ws_size >= ws_needed) {
    hipMemsetAsync(d_ws, 0, ws_needed, stream);
    lift_splat_kernel<<<NPIX, 256, 0, stream>>>(logits, ctx, gidx,
                                                (float*)d_ws);
    const int total = B * C * NV;
    transpose_kernel<<<(total + 255) / 256, 256, 0, stream>>>(
        (const float*)d_ws, out);
  } else {
    hipMemsetAsync(d_out, 0, (size_t)out_size * sizeof(float), stream);
    lift_splat_direct_kernel<<<NPIX, 256, 0, stream>>>(logits, ctx, gidx, out);
  }
}

// Round 3
// 233.085 us; speedup vs baseline: 1.3392x; 1.3392x over previous
//
#include <hip/hip_runtime.h>
#include <hip/hip_bf16.h>

// LSS (Lift-Splat-Shoot) voxel pooling via counting-sort + gather (no f32
// scatter atomics — round-1 counters showed 75.7M 4B atomics @318 Gops/s was
// the bound).
// B=2, N=6, D=112, H=16, W=44, C=80, BEV 128x128.

constexpr int B = 2, N = 6, D = 112, H = 16, W = 44, C = 80;
constexpr int HW = H * W;            // 704
constexpr int NPIX = B * N * HW;     // 8448 pixels
constexpr int NV = 128 * 128;        // 16384 voxels
constexpr int BNV = B * NV;          // 32768 bins
constexpr int PTS = NPIX * D;        // 946176 points (= 3696 * 256)

// ---- pass 1: per-pixel softmax, ctx transpose, voxel histogram ----
__global__ __launch_bounds__(256) void softmax_hist_kernel(
    const float* __restrict__ logits, const float* __restrict__ ctx,
    const int* __restrict__ gidx, float* __restrict__ probT,
    float* __restrict__ ctxT, int* __restrict__ counts) {
  const int t = threadIdx.x;
  const int pix = blockIdx.x;
  const int hw = pix % HW;
  const int bn = pix / HW;
  const int b = bn / N;

  const float* lg = logits + (size_t)bn * (D * HW) + hw;  // stride HW per d
  const int* gi = gidx + (size_t)bn * (D * HW) + hw;
  const float* cx = ctx + (size_t)bn * (C * HW) + hw;     // stride HW per c

  __shared__ float red[256];

  float v = -3.0e38f;
  int idx = 0;
  if (t < D) {
    v = lg[(size_t)t * HW];
    idx = gi[(size_t)t * HW];
  }
  if (t < C) ctxT[(size_t)pix * C + t] = cx[(size_t)t * HW];

  // block max
  red[t] = v;
  __syncthreads();
#pragma unroll
  for (int s = 128; s >= 1; s >>= 1) {
    if (t < s) red[t] = fmaxf(red[t], red[t + s]);
    __syncthreads();
  }
  const float m = red[0];
  __syncthreads();

  // exp + block sum
  const float e = (t < D) ? __expf(v - m) : 0.0f;
  red[t] = e;
  __syncthreads();
#pragma unroll
  for (int s = 128; s >= 1; s >>= 1) {
    if (t < s) red[t] += red[t + s];
    __syncthreads();
  }
  const float inv = 1.0f / red[0];

  if (t < D) {
    probT[(size_t)pix * D + t] = e * inv;       // coalesced
    atomicAdd(&counts[b * NV + idx], 1);        // 946K int atomics total
  }
}

// ---- pass 2: exclusive prefix sum over 32768 bins (single block) ----
__global__ __launch_bounds__(1024) void scan_kernel(
    const int* __restrict__ counts, int* __restrict__ offsets,
    int* __restrict__ cursor) {
  const int t = threadIdx.x;
  constexpr int CH = BNV / 1024;  // 32 elements per thread
  const int base = t * CH;

  int loc[CH];
  int s = 0;
#pragma unroll
  for (int i = 0; i < CH; ++i) {
    loc[i] = counts[base + i];
    s += loc[i];
  }

  __shared__ int sa[1024], sb[1024];
  sa[t] = s;
  __syncthreads();
  int* src = sa;
  int* dst = sb;
  for (int off = 1; off < 1024; off <<= 1) {
    dst[t] = src[t] + ((t >= off) ? src[t - off] : 0);
    __syncthreads();
    int* tmp = src;
    src = dst;
    dst = tmp;
  }
  int run = src[t] - s;  // exclusive prefix of this thread's chunk
#pragma unroll
  for (int i = 0; i < CH; ++i) {
    offsets[base + i] = run;
    cursor[base + i] = run;
    run += loc[i];
  }
}

// ---- pass 3: scatter point records into voxel-sorted order ----
__global__ __launch_bounds__(256) void scatter_kernel(
    const int* __restrict__ gidx, const float* __restrict__ probT,
    int* __restrict__ cursor, uint2* __restrict__ sorted) {
  const int pt = blockIdx.x * 256 + threadIdx.x;
  if (pt >= PTS) return;
  const int bn = pt / (D * HW);
  const int r = pt - bn * (D * HW);
  const int d = r / HW;
  const int hw = r - d * HW;
  const int b = bn / N;
  const int pix = bn * HW + hw;

  const float p = probT[(size_t)pix * D + d];
  const int idx = gidx[pt];  // coalesced
  const int bin = b * NV + idx;
  const int pos = atomicAdd(&cursor[bin], 1);
  sorted[pos] = make_uint2((unsigned)pix, __float_as_uint(p));
}

// ---- pass 4: gather per voxel, write [B,C,128,128] coalesced ----
// Block = 16 consecutive voxels of one b; wave w owns voxels w*4..w*4+3
// sequentially; lane l owns channel l (and l<16 also channel 64+l).
__global__ __launch_bounds__(256) void gather_kernel(
    const float* __restrict__ ctxT, const uint2* __restrict__ sorted,
    const int* __restrict__ offsets, const int* __restrict__ counts,
    float* __restrict__ out) {
  const int t = threadIdx.x;
  const int w = t >> 6;
  const int l = t & 63;
  constexpr int BPB = NV / 16;  // 1024 blocks per batch
  const int b = blockIdx.x / BPB;
  const int v0 = (blockIdx.x % BPB) * 16;

  __shared__ float s_acc[16][81];  // 81: conflict-free transposed read

  for (int vs = 0; vs < 4; ++vs) {
    const int vloc = w * 4 + vs;
    const int bin = b * NV + v0 + vloc;
    const int start = offsets[bin];
    const int cnt = counts[bin];
    float a0 = 0.0f, a1 = 0.0f;
    for (int k = 0; k < cnt; ++k) {
      const uint2 rec = sorted[start + k];
      const float p = __uint_as_float(rec.y);
      const float* row = ctxT + (size_t)rec.x * C;
      a0 += p * row[l];              // 256B coalesced, L2-resident
      if (l < 16) a1 += p * row[64 + l];
    }
    s_acc[vloc][l] = a0;
    if (l < 16) s_acc[vloc][64 + l] = a1;
  }
  __syncthreads();

  const size_t ob = (size_t)b * C * NV + v0;
#pragma unroll
  for (int ch = 0; ch < 5; ++ch) {
    const int idx = ch * 256 + t;
    const int c = idx >> 4;
    const int vi = idx & 15;
    out[ob + (size_t)c * NV + vi] = s_acc[vi][c];
  }
}

// ---- fallback: direct channel-major atomics (out must be zeroed) ----
__global__ __launch_bounds__(256) void lift_splat_direct_kernel(
    const float* __restrict__ logits, const float* __restrict__ ctx,
    const int* __restrict__ gidx, float* __restrict__ out) {
  const int t = threadIdx.x;
  const int pix = blockIdx.x;
  const int hw = pix % HW;
  const int bn = pix / HW;
  const int b = bn / N;

  const float* lg = logits + (size_t)bn * (D * HW) + hw;
  const int* gi = gidx + (size_t)bn * (D * HW) + hw;
  const float* cx = ctx + (size_t)bn * (C * HW) + hw;

  __shared__ float s_prob[D];
  __shared__ float s_ctx[C];
  __shared__ int s_idx[D];
  __shared__ float red[256];

  float v = -3.0e38f;
  if (t < D) {
    v = lg[(size_t)t * HW];
    s_idx[t] = gi[(size_t)t * HW];
  }
  if (t < C) s_ctx[t] = cx[(size_t)t * HW];

  red[t] = v;
  __syncthreads();
#pragma unroll
  for (int s = 128; s >= 1; s >>= 1) {
    if (t < s) red[t] = fmaxf(red[t], red[t + s]);
    __syncthreads();
  }
  const float m = red[0];
  __syncthreads();

  const float e = (t < D) ? __expf(v - m) : 0.0f;
  red[t] = e;
  __syncthreads();
#pragma unroll
  for (int s = 128; s >= 1; s >>= 1) {
    if (t < s) red[t] += red[t + s];
    __syncthreads();
  }
  const float inv = 1.0f / red[0];
  if (t < D) s_prob[t] = e * inv;
  __syncthreads();

  for (int f = t; f < D * C; f += 256) {
    const int d = f / C;
    const int c = f - d * C;
    atomicAdd(&out[((size_t)(b * C + c)) * NV + s_idx[d]],
              s_prob[d] * s_ctx[c]);
  }
}

extern "C" void kernel_launch(void* const* d_in, const int* in_sizes, int n_in,
                              void* d_out, int out_size, void* d_ws,
                              size_t ws_size, hipStream_t stream) {
  const float* logits = (const float*)d_in[0];
  const float* ctx = (const float*)d_in[1];
  const int* gidx = (const int*)d_in[2];
  float* out = (float*)d_out;

  // workspace layout (8B-aligned first)
  size_t off = 0;
  uint2* sorted = (uint2*)((char*)d_ws + off);
  off += (size_t)PTS * sizeof(uint2);                    // 7,569,408
  float* probT = (float*)((char*)d_ws + off);
  off += (size_t)NPIX * D * sizeof(float);               // 3,784,704
  float* ctxT = (float*)((char*)d_ws + off);
  off += (size_t)NPIX * C * sizeof(float);               // 2,703,360
  int* counts = (int*)((char*)d_ws + off);
  off += (size_t)BNV * sizeof(int);
  int* offsets = (int*)((char*)d_ws + off);
  off += (size_t)BNV * sizeof(int);
  int* cursor = (int*)((char*)d_ws + off);
  off += (size_t)BNV * sizeof(int);

  if (ws_size >= off) {
    (void)hipMemsetAsync(counts, 0, (size_t)BNV * sizeof(int), stream);
    softmax_hist_kernel<<<NPIX, 256, 0, stream>>>(logits, ctx, gidx, probT,
                                                  ctxT, counts);
    scan_kernel<<<1, 1024, 0, stream>>>(counts, offsets, cursor);
    scatter_kernel<<<PTS / 256, 256, 0, stream>>>(gidx, probT, cursor, sorted);
    gather_kernel<<<BNV / 16, 256, 0, stream>>>(ctxT, sorted, offsets, counts,
                                                out);
  } else {
    (void)hipMemsetAsync(d_out, 0, (size_t)out_size * sizeof(float), stream);
    lift_splat_direct_kernel<<<NPIX, 256, 0, stream>>>(logits, ctx, gidx, out);
  }
}

// Round 4
// 191.569 us; speedup vs baseline: 1.6294x; 1.2167x over previous
//
#include <hip/hip_runtime.h>
#include <hip/hip_bf16.h>

// LSS voxel pooling: counting-sort + gather, all passes coalesced.
// B=2, N=6, D=112, H=16, W=44, C=80, BEV 128x128.

constexpr int B = 2, N = 6, D = 112, H = 16, W = 44, C = 80;
constexpr int HW = H * W;            // 704 (= 11*64: blocks never straddle bn)
constexpr int NPIX = B * N * HW;     // 8448
constexpr int NV = 128 * 128;        // 16384
constexpr int BNV = B * NV;          // 32768
constexpr int PTS = NPIX * D;        // 946176 (= 3696*256)
constexpr int DHW = D * HW;          // 78848

// ---- pass A: softmax over D, output probD[bn][d][hw] (same layout as gidx)
// block = 64 pixels x 4 d-groups (28 logits each, kept in registers).
__global__ __launch_bounds__(256) void softmax_kernel(
    const float* __restrict__ logits, float* __restrict__ probD) {
  const int t = threadIdx.x;
  const int l = t & 63;   // pixel lane
  const int q = t >> 6;   // d-group
  const int pix = blockIdx.x * 64 + l;
  const int bn = pix / HW;
  const int hw = pix - bn * HW;
  const int d0 = q * 28;

  const float* lg = logits + (size_t)bn * DHW + hw;

  float x[28];
  float m = -3.0e38f;
#pragma unroll
  for (int j = 0; j < 28; ++j) {
    x[j] = lg[(size_t)(d0 + j) * HW];   // coalesced across l
    m = fmaxf(m, x[j]);
  }

  __shared__ float redm[4][64];
  __shared__ float reds[4][64];
  redm[q][l] = m;
  __syncthreads();
  m = fmaxf(fmaxf(redm[0][l], redm[1][l]), fmaxf(redm[2][l], redm[3][l]));

  float s = 0.0f;
#pragma unroll
  for (int j = 0; j < 28; ++j) {
    x[j] = __expf(x[j] - m);
    s += x[j];
  }
  reds[q][l] = s;
  __syncthreads();
  const float inv =
      1.0f / (reds[0][l] + reds[1][l] + reds[2][l] + reds[3][l]);

  float* pd = probD + (size_t)bn * DHW + hw;
#pragma unroll
  for (int j = 0; j < 28; ++j) pd[(size_t)(d0 + j) * HW] = x[j] * inv;
}

// ---- pass B: ctx[bn][c][hw] -> ctxT[pix][c], LDS tile, both sides coalesced
__global__ __launch_bounds__(256) void ctx_transpose_kernel(
    const float* __restrict__ ctx, float* __restrict__ ctxT) {
  __shared__ float s[C][65];
  const int t = threadIdx.x;
  const int bn = blockIdx.x / (HW / 64);
  const int hw0 = (blockIdx.x % (HW / 64)) * 64;

  const float* src = ctx + (size_t)bn * C * HW + hw0;
#pragma unroll
  for (int it = 0; it < (C * 64) / 256; ++it) {
    const int idx = it * 256 + t;
    const int c = idx >> 6;
    const int i = idx & 63;
    s[c][i] = src[(size_t)c * HW + i];
  }
  __syncthreads();

  float* dst = ctxT + ((size_t)bn * HW + hw0) * C;
#pragma unroll
  for (int it = 0; it < (C * 64) / 256; ++it) {
    const int j = it * 256 + t;
    const int p = j / C;
    const int c = j - p * C;
    dst[j] = s[c][p];
  }
}

// ---- pass C: histogram of voxel bins ----
__global__ __launch_bounds__(256) void hist_kernel(
    const int* __restrict__ gidx, int* __restrict__ counts) {
  const int pt = blockIdx.x * 256 + threadIdx.x;
  if (pt >= PTS) return;
  const int bn = pt / DHW;
  const int b = bn / N;
  atomicAdd(&counts[b * NV + gidx[pt]], 1);
}

// ---- pass D: exclusive prefix over 32768 bins (single block) ----
__global__ __launch_bounds__(1024) void scan_kernel(
    const int* __restrict__ counts, int* __restrict__ offsets,
    int* __restrict__ cursor) {
  const int t = threadIdx.x;
  constexpr int CH = BNV / 1024;  // 32
  const int base = t * CH;

  int loc[CH];
  int s = 0;
#pragma unroll
  for (int i = 0; i < CH; ++i) {
    loc[i] = counts[base + i];
    s += loc[i];
  }

  __shared__ int sa[1024], sb[1024];
  sa[t] = s;
  __syncthreads();
  int* src = sa;
  int* dst = sb;
  for (int off = 1; off < 1024; off <<= 1) {
    dst[t] = src[t] + ((t >= off) ? src[t - off] : 0);
    __syncthreads();
    int* tmp = src;
    src = dst;
    dst = tmp;
  }
  int run = src[t] - s;
#pragma unroll
  for (int i = 0; i < CH; ++i) {
    offsets[base + i] = run;
    cursor[base + i] = run;
    run += loc[i];
  }
}

// ---- pass E: scatter (pix, prob) records into voxel-sorted order ----
__global__ __launch_bounds__(256) void scatter_kernel(
    const int* __restrict__ gidx, const float* __restrict__ probD,
    int* __restrict__ cursor, uint2* __restrict__ sorted) {
  const int pt = blockIdx.x * 256 + threadIdx.x;
  if (pt >= PTS) return;
  const int bn = pt / DHW;
  const int r = pt - bn * DHW;
  const int hw = r % HW;
  const int b = bn / N;
  const int pix = bn * HW + hw;

  const float p = probD[pt];       // coalesced (same layout as gidx)
  const int bin = b * NV + gidx[pt];
  const int pos = atomicAdd(&cursor[bin], 1);
  sorted[pos] = make_uint2((unsigned)pix, __float_as_uint(p));
}

// ---- pass F: gather per voxel, unroll-4 for ILP, write [B,C,v] coalesced
// Block = 16 voxels; wave w owns voxels w*4..w*4+3; lane l = channel l
// (and 64+l for l<16).
__global__ __launch_bounds__(256) void gather_kernel(
    const float* __restrict__ ctxT, const uint2* __restrict__ sorted,
    const int* __restrict__ offsets, const int* __restrict__ counts,
    float* __restrict__ out) {
  const int t = threadIdx.x;
  const int w = t >> 6;
  const int l = t & 63;
  constexpr int BPB = NV / 16;
  const int b = blockIdx.x / BPB;
  const int v0 = (blockIdx.x % BPB) * 16;

  __shared__ float s_acc[16][81];

  for (int vs = 0; vs < 4; ++vs) {
    const int vloc = w * 4 + vs;
    const int bin = b * NV + v0 + vloc;
    const int start = __builtin_amdgcn_readfirstlane(offsets[bin]);
    const int cnt = __builtin_amdgcn_readfirstlane(counts[bin]);
    float a0 = 0.0f, a1 = 0.0f;
    int k = 0;
    for (; k + 4 <= cnt; k += 4) {
      const uint2 r0 = sorted[start + k + 0];
      const uint2 r1 = sorted[start + k + 1];
      const uint2 r2 = sorted[start + k + 2];
      const uint2 r3 = sorted[start + k + 3];
      const float* w0 = ctxT + (size_t)r0.x * C;
      const float* w1 = ctxT + (size_t)r1.x * C;
      const float* w2 = ctxT + (size_t)r2.x * C;
      const float* w3 = ctxT + (size_t)r3.x * C;
      const float p0 = __uint_as_float(r0.y);
      const float p1 = __uint_as_float(r1.y);
      const float p2 = __uint_as_float(r2.y);
      const float p3 = __uint_as_float(r3.y);
      a0 += p0 * w0[l];
      a0 += p1 * w1[l];
      a0 += p2 * w2[l];
      a0 += p3 * w3[l];
      if (l < 16) {
        a1 += p0 * w0[64 + l];
        a1 += p1 * w1[64 + l];
        a1 += p2 * w2[64 + l];
        a1 += p3 * w3[64 + l];
      }
    }
    for (; k < cnt; ++k) {
      const uint2 r = sorted[start + k];
      const float p = __uint_as_float(r.y);
      const float* row = ctxT + (size_t)r.x * C;
      a0 += p * row[l];
      if (l < 16) a1 += p * row[64 + l];
    }
    s_acc[vloc][l] = a0;
    if (l < 16) s_acc[vloc][64 + l] = a1;
  }
  __syncthreads();

  const size_t ob = (size_t)b * C * NV + v0;
#pragma unroll
  for (int ch = 0; ch < 5; ++ch) {
    const int idx = ch * 256 + t;
    const int c = idx >> 4;
    const int vi = idx & 15;
    out[ob + (size_t)c * NV + vi] = s_acc[vi][c];
  }
}

// ---- fallback: direct channel-major atomics (out must be zeroed) ----
__global__ __launch_bounds__(256) void lift_splat_direct_kernel(
    const float* __restrict__ logits, const float* __restrict__ ctx,
    const int* __restrict__ gidx, float* __restrict__ out) {
  const int t = threadIdx.x;
  const int pix = blockIdx.x;
  const int hw = pix % HW;
  const int bn = pix / HW;
  const int b = bn / N;

  const float* lg = logits + (size_t)bn * DHW + hw;
  const int* gi = gidx + (size_t)bn * DHW + hw;
  const float* cx = ctx + (size_t)bn * (C * HW) + hw;

  __shared__ float s_prob[D];
  __shared__ float s_ctx[C];
  __shared__ int s_idx[D];
  __shared__ float red[256];

  float v = -3.0e38f;
  if (t < D) {
    v = lg[(size_t)t * HW];
    s_idx[t] = gi[(size_t)t * HW];
  }
  if (t < C) s_ctx[t] = cx[(size_t)t * HW];

  red[t] = v;
  __syncthreads();
#pragma unroll
  for (int s = 128; s >= 1; s >>= 1) {
    if (t < s) red[t] = fmaxf(red[t], red[t + s]);
    __syncthreads();
  }
  const float m = red[0];
  __syncthreads();

  const float e = (t < D) ? __expf(v - m) : 0.0f;
  red[t] = e;
  __syncthreads();
#pragma unroll
  for (int s = 128; s >= 1; s >>= 1) {
    if (t < s) red[t] += red[t + s];
    __syncthreads();
  }
  const float inv = 1.0f / red[0];
  if (t < D) s_prob[t] = e * inv;
  __syncthreads();

  for (int f = t; f < D * C; f += 256) {
    const int d = f / C;
    const int c = f - d * C;
    atomicAdd(&out[((size_t)(b * C + c)) * NV + s_idx[d]],
              s_prob[d] * s_ctx[c]);
  }
}

extern "C" void kernel_launch(void* const* d_in, const int* in_sizes, int n_in,
                              void* d_out, int out_size, void* d_ws,
                              size_t ws_size, hipStream_t stream) {
  const float* logits = (const float*)d_in[0];
  const float* ctx = (const float*)d_in[1];
  const int* gidx = (const int*)d_in[2];
  float* out = (float*)d_out;

  size_t off = 0;
  uint2* sorted = (uint2*)((char*)d_ws + off);
  off += (size_t)PTS * sizeof(uint2);
  float* probD = (float*)((char*)d_ws + off);
  off += (size_t)PTS * sizeof(float);
  float* ctxT = (float*)((char*)d_ws + off);
  off += (size_t)NPIX * C * sizeof(float);
  int* counts = (int*)((char*)d_ws + off);
  off += (size_t)BNV * sizeof(int);
  int* offsets = (int*)((char*)d_ws + off);
  off += (size_t)BNV * sizeof(int);
  int* cursor = (int*)((char*)d_ws + off);
  off += (size_t)BNV * sizeof(int);

  if (ws_size >= off) {
    (void)hipMemsetAsync(counts, 0, (size_t)BNV * sizeof(int), stream);
    softmax_kernel<<<NPIX / 64, 256, 0, stream>>>(logits, probD);
    ctx_transpose_kernel<<<B * N * (HW / 64), 256, 0, stream>>>(ctx, ctxT);
    hist_kernel<<<PTS / 256, 256, 0, stream>>>(gidx, counts);
    scan_kernel<<<1, 1024, 0, stream>>>(counts, offsets, cursor);
    scatter_kernel<<<PTS / 256, 256, 0, stream>>>(gidx, probD, cursor, sorted);
    gather_kernel<<<BNV / 16, 256, 0, stream>>>(ctxT, sorted, offsets, counts,
                                                out);
  } else {
    (void)hipMemsetAsync(d_out, 0, (size_t)out_size * sizeof(float), stream);
    lift_splat_direct_kernel<<<NPIX, 256, 0, stream>>>(logits, ctx, gidx, out);
  }
}